// Round 1
// baseline (515.657 us; speedup 1.0000x reference)
//
#include <hip/hip_runtime.h>

#define NXg 4096
#define NYg 4096

__global__ __launch_bounds__(256) void fdtd_step_kernel(
    const float* __restrict__ ez, const float* __restrict__ hx,
    const float* __restrict__ hy, const float* __restrict__ eps,
    const float* __restrict__ mu, const float* __restrict__ sigma,
    float* __restrict__ ez_out, float* __restrict__ hx_out,
    float* __restrict__ hy_out)
{
    const int j = blockIdx.x * blockDim.x + threadIdx.x;   // last axis, stride 1
    const int i = blockIdx.y;                              // axis 0, stride NY
    if (j >= NYg) return;
    const long idx = (long)i * NYg + j;

    constexpr float DT = 5e-4f;
    constexpr float DX = 1e-3f;
    constexpr float DY = 1e-3f;
    const float inv2dx = 1.0f / (2.0f * DX);
    const float inv2dy = 1.0f / (2.0f * DY);

    const bool jin = (j >= 1) && (j < NYg - 1);
    const bool iin = (i >= 1) && (i < NXg - 1);
    const bool interior = iin && jin;

    const float ezC = ez[idx];
    const float invmuC = 1.0f / mu[idx];

    // H update at the center point
    const float ddy_ezC = interior ? (ez[idx + 1] - ez[idx - 1]) * inv2dy : 0.0f;
    const float ddx_ezC = interior ? (ez[idx + NYg] - ez[idx - NYg]) * inv2dx : 0.0f;

    const float hx_new = hx[idx] - DT * ddy_ezC * invmuC;
    const float hy_new = hy[idx] + DT * ddx_ezC * invmuC;

    // Ez update from curl of the NEW H fields (recomputed at neighbors)
    float curl = 0.0f;
    if (interior) {
        // hy_new at (i+1, j): needs ddx(ez) there; zero if (i+1) not interior row
        const float dExP = (i < NXg - 2) ? (ez[idx + 2 * NYg] - ezC) * inv2dx : 0.0f;
        const float dExM = (i >= 2)      ? (ezC - ez[idx - 2 * NYg]) * inv2dx : 0.0f;
        const float hyP = hy[idx + NYg] + DT * dExP / mu[idx + NYg];
        const float hyM = hy[idx - NYg] + DT * dExM / mu[idx - NYg];

        // hx_new at (i, j±1)
        const float dEyP = (j < NYg - 2) ? (ez[idx + 2] - ezC) * inv2dy : 0.0f;
        const float dEyM = (j >= 2)      ? (ezC - ez[idx - 2]) * inv2dy : 0.0f;
        const float hxP = hx[idx + 1] - DT * dEyP / mu[idx + 1];
        const float hxM = hx[idx - 1] - DT * dEyM / mu[idx - 1];

        curl = (hyP - hyM) * inv2dx - (hxP - hxM) * inv2dy;
    }

    const float ep = eps[idx];
    const float s  = sigma[idx] * DT / (2.0f * ep);
    const float Ap = 1.0f + s;
    const float Am = 1.0f - s;
    const float ez_new = (Am / Ap) * ezC + (DT / (Ap * ep)) * curl;

    ez_out[idx] = ez_new;
    hx_out[idx] = hx_new;
    hy_out[idx] = hy_new;
}

extern "C" void kernel_launch(void* const* d_in, const int* in_sizes, int n_in,
                              void* d_out, int out_size, void* d_ws, size_t ws_size,
                              hipStream_t stream) {
    const float* ez    = (const float*)d_in[0];
    const float* hx    = (const float*)d_in[1];
    const float* hy    = (const float*)d_in[2];
    const float* eps   = (const float*)d_in[3];
    const float* mu    = (const float*)d_in[4];
    const float* sigma = (const float*)d_in[5];

    const long N = (long)NXg * NYg;
    float* out    = (float*)d_out;
    float* ez_out = out;
    float* hx_out = out + N;
    float* hy_out = out + 2 * N;

    dim3 block(256, 1, 1);
    dim3 grid(NYg / 256, NXg, 1);
    fdtd_step_kernel<<<grid, block, 0, stream>>>(ez, hx, hy, eps, mu, sigma,
                                                 ez_out, hx_out, hy_out);
}

// Round 3
// 460.494 us; speedup vs baseline: 1.1198x; 1.1198x over previous
//
#include <hip/hip_runtime.h>

#define NXg 4096
#define NYg 4096

typedef float v4f __attribute__((ext_vector_type(4)));

__global__ __launch_bounds__(256) void fdtd_step_kernel(
    const float* __restrict__ ez, const float* __restrict__ hx,
    const float* __restrict__ hy, const float* __restrict__ eps,
    const float* __restrict__ mu, const float* __restrict__ sigma,
    float* __restrict__ ez_out, float* __restrict__ hx_out,
    float* __restrict__ hy_out)
{
    const int j0 = (blockIdx.x * blockDim.x + threadIdx.x) * 4;  // 4 elems/thread
    const int i  = blockIdx.y;
    const long row = (long)i * NYg;
    const long idx = row + j0;

    constexpr float DT = 5e-4f;
    constexpr float inv2dx = 500.0f;   // 1/(2*DX)
    constexpr float inv2dy = 500.0f;   // 1/(2*DY)

    const bool iin = (i >= 1) && (i < NXg - 1);
    const bool iP2 = (i < NXg - 2);
    const bool iM2 = (i >= 2);

    // clamped row indices (clamped values only feed masked lanes)
    const int rm1 = (i >= 1) ? i - 1 : i;
    const int rp1 = (i < NXg - 1) ? i + 1 : i;
    const int rm2 = (i >= 2) ? i - 2 : i;
    const int rp2 = (i < NXg - 2) ? i + 2 : i;

    // clamped j-neighbor vector offsets (clamped values only feed masked slots)
    const long jm = (j0 == 0) ? (long)j0 : (long)j0 - 4;
    const long jp = (j0 == NYg - 4) ? (long)j0 : (long)j0 + 4;

    const v4f ezL  = *(const v4f*)(ez + row + jm);
    const v4f ezC4 = *(const v4f*)(ez + idx);
    const v4f ezR  = *(const v4f*)(ez + row + jp);
    const v4f ezU  = *(const v4f*)(ez + (long)rp1 * NYg + j0);
    const v4f ezD  = *(const v4f*)(ez + (long)rm1 * NYg + j0);
    const v4f ezU2 = *(const v4f*)(ez + (long)rp2 * NYg + j0);
    const v4f ezD2 = *(const v4f*)(ez + (long)rm2 * NYg + j0);

    const v4f hxL  = *(const v4f*)(hx + row + jm);
    const v4f hxC4 = *(const v4f*)(hx + idx);
    const v4f hxR  = *(const v4f*)(hx + row + jp);

    const v4f hyC4 = *(const v4f*)(hy + idx);
    const v4f hyU  = *(const v4f*)(hy + (long)rp1 * NYg + j0);
    const v4f hyD  = *(const v4f*)(hy + (long)rm1 * NYg + j0);

    const v4f muL  = *(const v4f*)(mu + row + jm);
    const v4f muC4 = *(const v4f*)(mu + idx);
    const v4f muR  = *(const v4f*)(mu + row + jp);
    const v4f muU  = *(const v4f*)(mu + (long)rp1 * NYg + j0);
    const v4f muD  = *(const v4f*)(mu + (long)rm1 * NYg + j0);

    const v4f ep4  = *(const v4f*)(eps + idx);
    const v4f sg4  = *(const v4f*)(sigma + idx);

    // 12-wide windows for j-neighbor access (center elem e is at w[e+4])
    float ezw[12], hxw[12], muw[12];
    *(v4f*)&ezw[0] = ezL;  *(v4f*)&ezw[4] = ezC4;  *(v4f*)&ezw[8] = ezR;
    *(v4f*)&hxw[0] = hxL;  *(v4f*)&hxw[4] = hxC4;  *(v4f*)&hxw[8] = hxR;
    *(v4f*)&muw[0] = muL;  *(v4f*)&muw[4] = muC4;  *(v4f*)&muw[8] = muR;

    v4f ezo, hxo, hyo;

#pragma unroll
    for (int e = 0; e < 4; ++e) {
        const int j = j0 + e;
        const bool jin = (j >= 1) && (j < NYg - 1);
        const bool interior = iin && jin;

        const float ezCv  = ezw[e + 4];
        const float invmu = __builtin_amdgcn_rcpf(muw[e + 4]);

        const float ddy = interior ? (ezw[e + 5] - ezw[e + 3]) * inv2dy : 0.0f;
        const float ddx = interior ? (ezU[e] - ezD[e]) * inv2dx : 0.0f;

        const float hx_new = hxw[e + 4] - DT * ddy * invmu;
        const float hy_new = hyC4[e]    + DT * ddx * invmu;

        float curl = 0.0f;
        if (interior) {
            const float dExP = iP2 ? (ezU2[e] - ezCv) * inv2dx : 0.0f;
            const float dExM = iM2 ? (ezCv - ezD2[e]) * inv2dx : 0.0f;
            const float hyP = hyU[e] + DT * dExP * __builtin_amdgcn_rcpf(muU[e]);
            const float hyM = hyD[e] + DT * dExM * __builtin_amdgcn_rcpf(muD[e]);

            const float dEyP = (j < NYg - 2) ? (ezw[e + 6] - ezCv) * inv2dy : 0.0f;
            const float dEyM = (j >= 2)      ? (ezCv - ezw[e + 2]) * inv2dy : 0.0f;
            const float hxP = hxw[e + 5] - DT * dEyP * __builtin_amdgcn_rcpf(muw[e + 5]);
            const float hxM = hxw[e + 3] - DT * dEyM * __builtin_amdgcn_rcpf(muw[e + 3]);

            curl = (hyP - hyM) * inv2dx - (hxP - hxM) * inv2dy;
        }

        const float ep  = ep4[e];
        const float rep = __builtin_amdgcn_rcpf(ep);
        const float s   = sg4[e] * DT * 0.5f * rep;
        const float Ap  = 1.0f + s;
        const float Am  = 1.0f - s;
        const float rAp = __builtin_amdgcn_rcpf(Ap);

        ezo[e] = Am * rAp * ezCv + DT * rAp * rep * curl;
        hxo[e] = hx_new;
        hyo[e] = hy_new;
    }

    __builtin_nontemporal_store(ezo, (v4f*)(ez_out + idx));
    __builtin_nontemporal_store(hxo, (v4f*)(hx_out + idx));
    __builtin_nontemporal_store(hyo, (v4f*)(hy_out + idx));
}

extern "C" void kernel_launch(void* const* d_in, const int* in_sizes, int n_in,
                              void* d_out, int out_size, void* d_ws, size_t ws_size,
                              hipStream_t stream) {
    const float* ez    = (const float*)d_in[0];
    const float* hx    = (const float*)d_in[1];
    const float* hy    = (const float*)d_in[2];
    const float* eps   = (const float*)d_in[3];
    const float* mu    = (const float*)d_in[4];
    const float* sigma = (const float*)d_in[5];

    const long N = (long)NXg * NYg;
    float* out    = (float*)d_out;
    float* ez_out = out;
    float* hx_out = out + N;
    float* hy_out = out + 2 * N;

    dim3 block(256, 1, 1);
    dim3 grid(NYg / (256 * 4), NXg, 1);
    fdtd_step_kernel<<<grid, block, 0, stream>>>(ez, hx, hy, eps, mu, sigma,
                                                 ez_out, hx_out, hy_out);
}